// Round 3
// baseline (160.760 us; speedup 1.0000x reference)
//
#include <hip/hip_runtime.h>

#define C 4096
#define NROWS 16384
#define PARTS 256   // row-slices for colsum partials

typedef float f32x4 __attribute__((ext_vector_type(4)));

// ---------------------------------------------------------------------------
// Kernel 1: per-slice column partial sums. grid=(C/1024, PARTS), block=256.
// Whole grid (1024 blocks) is co-resident -> x recency in L3 ends up striped
// by row%64 (row 63 of each slice read last). scale_kernel exploits this.
// ---------------------------------------------------------------------------
__global__ void colsum_partial(const float* __restrict__ x, float* __restrict__ part) {
    const int c4 = blockIdx.x * blockDim.x + threadIdx.x;   // float4 column, 0..1023
    const int rows_per = NROWS / PARTS;                      // 64
    const int r0 = blockIdx.y * rows_per;
    const f32x4* xv = (const f32x4*)x;
    f32x4 acc = {0.f, 0.f, 0.f, 0.f};
#pragma unroll 4
    for (int r = 0; r < rows_per; ++r) {
        acc += xv[(size_t)(r0 + r) * (C / 4) + c4];
    }
    ((f32x4*)part)[(size_t)blockIdx.y * (C / 4) + c4] = acc;
}

// ---------------------------------------------------------------------------
// Kernel 2: fold PARTS partial rows -> gsum [C]. Reads 4 MiB (L2-hot).
// ---------------------------------------------------------------------------
__global__ void colsum_reduce(const float* __restrict__ part, float* __restrict__ gsum) {
    const int c = blockIdx.x * blockDim.x + threadIdx.x;     // 0..4095
    float s = 0.f;
#pragma unroll 8
    for (int r = 0; r < PARTS; ++r) s += part[(size_t)r * C + c];
    gsum[c] = s;
}

// ---------------------------------------------------------------------------
// Kernel 3: y[i] = sigmoid( sf * ( dot(W[i,:], gsum)/NROWS + b[i] ) )
// W via nontemporal loads: evict-first, keep x resident in L3.
// ---------------------------------------------------------------------------
__global__ void matvec_kernel(const float* __restrict__ W,
                              const float* __restrict__ b,
                              const float* __restrict__ gsum,
                              const int* __restrict__ sf,
                              float* __restrict__ scale_out) {
    const int row = blockIdx.x;
    const int t = threadIdx.x;  // 256
    const f32x4* wv = (const f32x4*)(W + (size_t)row * C);
    const f32x4* gv = (const f32x4*)gsum;
    float acc = 0.f;
#pragma unroll
    for (int k = 0; k < 4; ++k) {
        const int j4 = t + k * 256;          // coalesced per k
        const f32x4 w = __builtin_nontemporal_load(wv + j4);
        const f32x4 g = gv[j4];
        acc += w.x * g.x + w.y * g.y + w.z * g.z + w.w * g.w;
    }
#pragma unroll
    for (int off = 32; off > 0; off >>= 1) acc += __shfl_down(acc, off);
    __shared__ float red[4];
    if ((t & 63) == 0) red[t >> 6] = acc;
    __syncthreads();
    if (t == 0) {
        const float y = (red[0] + red[1] + red[2] + red[3]) * (1.0f / NROWS) + b[row];
        const float z = y * (float)sf[0];
        const float s = 1.0f / (1.0f + __expf(-z));
        scale_out[row] = s;
    }
}

// ---------------------------------------------------------------------------
// Kernel 4: out[n][c] = x[n][c] * s[c], scanning rows in DESCENDING residue
// (row%64) order to match colsum's L3 recency stripe (newest-first re-read).
// Grid = exactly 2048 blocks x 256 threads; each of the 32 iterations sweeps
// 2 residue classes grid-wide, in order res 63,62 ... 1,0.
// x loads nt (dead after use), out stores nt (don't evict resident x).
// ---------------------------------------------------------------------------
__global__ void scale_kernel(const float* __restrict__ x,
                             const float* __restrict__ s,
                             float* __restrict__ out) {
    const f32x4* xv = (const f32x4*)x;
    const f32x4* sv = (const f32x4*)s;
    f32x4* ov = (f32x4*)out;
    const unsigned gid = blockIdx.x * 256u + threadIdx.x;    // 0..524287
    for (int it = 0; it < 32; ++it) {
        const unsigned j = it * 524288u + gid;               // permuted float4 index, 0..16M-1
        const unsigned c4 = j & 1023u;                       // column float4
        const unsigned t = j >> 10;
        const unsigned ric = t & 255u;                       // row-in-class
        const unsigned cls = t >> 8;                         // 0..63, processed in order
        const unsigned res = 63u - cls;                      // residue: newest stripe first
        const unsigned row = res + (ric << 6);
        const size_t idx = (size_t)row * 1024u + c4;
        f32x4 v = __builtin_nontemporal_load(xv + idx);
        v *= sv[c4];
        __builtin_nontemporal_store(v, ov + idx);
    }
}

extern "C" void kernel_launch(void* const* d_in, const int* in_sizes, int n_in,
                              void* d_out, int out_size, void* d_ws, size_t ws_size,
                              hipStream_t stream) {
    const float* x = (const float*)d_in[0];   // [NROWS, C] fp32
    const float* W = (const float*)d_in[1];   // [C, C] fp32
    const float* b = (const float*)d_in[2];   // [C] fp32
    const int* sf  = (const int*)d_in[3];     // scalar int

    float* out = (float*)d_out;               // [NROWS*C] x_out ++ [C] x_scale
    float* scale_tail = out + (size_t)NROWS * C;

    float* part = (float*)d_ws;               // [PARTS][C] partial sums (4 MiB)
    float* gsum = part + (size_t)PARTS * C;   // [C]

    colsum_partial<<<dim3(C / 1024, PARTS), 256, 0, stream>>>(x, part);
    colsum_reduce<<<C / 256, 256, 0, stream>>>(part, gsum);
    matvec_kernel<<<C, 256, 0, stream>>>(W, b, gsum, sf, scale_tail);
    scale_kernel<<<2048, 256, 0, stream>>>(x, scale_tail, out);
}